// Round 3
// baseline (125.278 us; speedup 1.0000x reference)
//
#include <hip/hip_runtime.h>
#include <math.h>

// floss: weighted BCE with per-batch argmax-centroid weights.
// input/target: [256, 1, 224, 224] fp32. Output: scalar fp32 mean.
//
// R3: 3-kernel split to break the 1-block/CU occupancy cap of the fused
// design (R2 was latency-bound at ~40 us, 16 waves/CU, 2 barriers):
//   k1 centroid: 256 blocks x 1024 thr, branchless streaming argmax stats
//   k2 bce:      1024 blocks x 512 thr (4 blocks/image -> 32 waves/CU),
//                log2-domain BCE with ln2 folded into the weight constant,
//                per-block partial sums to ws (no same-address atomics)
//   k3 reduce:   1 block sums 1024 partials -> out

#define WIMG 224
#define WW (WIMG * WIMG)        // 50176
#define NQ (WW / 4)             // 12544 quads; 56 quads/row
#define NB 256
#define K1_THREADS 1024
#define NPARTB 4                // blocks per image in k2
#define QPB (NQ / NPARTB)       // 3136 quads per k2 block
#define K2_THREADS 512
#define NPART (NB * NPARTB)     // 1024 partials
#define LN2 0.69314718055994530942f
#define CLAMP2 (-144.269504088896340736f)   // -100 / ln2, clamp in log2 domain

__global__ __launch_bounds__(K1_THREADS) void centroid_kernel(
    const float* __restrict__ target, float* __restrict__ xy)
{
    const int b   = blockIdx.x;
    const int tid = threadIdx.x;
    const float4* __restrict__ t4 = (const float4*)(target + (size_t)b * WW);

    // branchless streaming (max, cnt, sum_i, sum_j)
    float m = -1.0f, cnt = 0.0f, si = 0.0f, sj = 0.0f;
    for (int q = tid; q < NQ; q += K1_THREADS) {
        float4 v = t4[q];
        int i  = q / 56;
        int j0 = (q - i * 56) * 4;
        float fi = (float)i;
        float vv[4] = {v.x, v.y, v.z, v.w};
        #pragma unroll
        for (int k = 0; k < 4; ++k) {
            float val = vv[k];
            float fj  = (float)(j0 + k);
            bool gt = val > m;
            bool eq = val == m;
            cnt = gt ? 1.0f : (cnt + (eq ? 1.0f : 0.0f));
            si  = gt ? fi   : (si  + (eq ? fi   : 0.0f));
            sj  = gt ? fj   : (sj  + (eq ? fj   : 0.0f));
            m   = fmaxf(m, val);
        }
    }
    #pragma unroll
    for (int off = 32; off > 0; off >>= 1) {
        float m2  = __shfl_down(m,   off);
        float c2  = __shfl_down(cnt, off);
        float si2 = __shfl_down(si,  off);
        float sj2 = __shfl_down(sj,  off);
        bool gt = m2 > m, eq = m2 == m;
        cnt = gt ? c2  : (cnt + (eq ? c2  : 0.0f));
        si  = gt ? si2 : (si  + (eq ? si2 : 0.0f));
        sj  = gt ? sj2 : (sj  + (eq ? sj2 : 0.0f));
        m   = fmaxf(m, m2);
    }
    __shared__ float sm[16], sc[16], ssi[16], ssj[16];
    const int lane = tid & 63, wid = tid >> 6;
    if (lane == 0) { sm[wid] = m; sc[wid] = cnt; ssi[wid] = si; ssj[wid] = sj; }
    __syncthreads();
    if (tid == 0) {
        float M = sm[0], C = sc[0], SI = ssi[0], SJ = ssj[0];
        #pragma unroll
        for (int w = 1; w < 16; ++w) {
            float mw = sm[w];
            bool gt = mw > M, eq = mw == M;
            C  = gt ? sc[w]  : (C  + (eq ? sc[w]  : 0.0f));
            SI = gt ? ssi[w] : (SI + (eq ? ssi[w] : 0.0f));
            SJ = gt ? ssj[w] : (SJ + (eq ? ssj[w] : 0.0f));
            M  = fmaxf(M, mw);
        }
        xy[2 * b]     = SI / C;   // x = mean row index
        xy[2 * b + 1] = SJ / C;   // y = mean col index
    }
}

__global__ __launch_bounds__(K2_THREADS) void bce_kernel(
    const float* __restrict__ input,
    const float* __restrict__ target,
    const float* __restrict__ xy,
    float* __restrict__ partial)
{
    const int blk  = blockIdx.x;
    const int b    = blk >> 2;          // image
    const int part = blk & 3;           // quarter
    const int tid  = threadIdx.x;
    const float x = xy[2 * b];
    const float y = xy[2 * b + 1];
    const float4* __restrict__ t4 = (const float4*)(target + (size_t)b * WW);
    const float4* __restrict__ p4 = (const float4*)(input  + (size_t)b * WW);
    const int qbase = part * QPB;
    const float Kc = -(float)WIMG * LN2;   // fold -ln2 into the weight

    float acc = 0.0f;
    for (int ql = tid; ql < QPB; ql += K2_THREADS) {
        int q  = qbase + ql;
        float4 tv = t4[q];
        float4 pv = p4[q];
        int i  = q / 56;
        int j0 = (q - i * 56) * 4;
        float di  = (float)i - x;
        float di2 = di * di;
        float tt[4] = {tv.x, tv.y, tv.z, tv.w};
        float pp[4] = {pv.x, pv.y, pv.z, pv.w};
        #pragma unroll
        for (int k = 0; k < 4; ++k) {
            float dj = (float)(j0 + k) - y;
            float s  = __builtin_amdgcn_sqrtf(di2 + dj * dj);
            float wf = Kc * __builtin_amdgcn_rcpf(s + 1.0f);   // = -224*ln2/(sqrt+1)
            float p = pp[k], t = tt[k];
            float lp2  = fmaxf(__builtin_amdgcn_logf(p),        CLAMP2);
            float l1p2 = fmaxf(__builtin_amdgcn_logf(1.0f - p), CLAMP2);
            // weight*bce = wf * (t*lp2 + (1-t)*l1p2)
            acc += wf * (l1p2 + t * (lp2 - l1p2));
        }
    }
    #pragma unroll
    for (int off = 32; off > 0; off >>= 1) acc += __shfl_down(acc, off);
    __shared__ float sred[8];
    const int lane = tid & 63, wid = tid >> 6;
    if (lane == 0) sred[wid] = acc;
    __syncthreads();
    if (tid == 0) {
        float ssum = 0.0f;
        #pragma unroll
        for (int w = 0; w < 8; ++w) ssum += sred[w];
        partial[blk] = ssum;
    }
}

__global__ __launch_bounds__(NPART) void final_reduce(
    const float* __restrict__ partial, float* __restrict__ out, float inv_total)
{
    const int tid = threadIdx.x;
    float v = partial[tid];
    #pragma unroll
    for (int off = 32; off > 0; off >>= 1) v += __shfl_down(v, off);
    __shared__ float sred[16];
    const int lane = tid & 63, wid = tid >> 6;
    if (lane == 0) sred[wid] = v;
    __syncthreads();
    if (tid == 0) {
        float s = 0.0f;
        #pragma unroll
        for (int w = 0; w < 16; ++w) s += sred[w];
        out[0] = s * inv_total;
    }
}

extern "C" void kernel_launch(void* const* d_in, const int* in_sizes, int n_in,
                              void* d_out, int out_size, void* d_ws, size_t ws_size,
                              hipStream_t stream) {
    const float* input  = (const float*)d_in[0];
    const float* target = (const float*)d_in[1];
    float* out = (float*)d_out;
    float* xy      = (float*)d_ws;            // 512 floats
    float* partial = (float*)d_ws + 512;      // 1024 floats

    centroid_kernel<<<NB, K1_THREADS, 0, stream>>>(target, xy);
    bce_kernel<<<NPART, K2_THREADS, 0, stream>>>(input, target, xy, partial);
    const float inv_total = 1.0f / (256.0f * 224.0f * 224.0f);
    final_reduce<<<1, NPART, 0, stream>>>(partial, out, inv_total);
}